// Round 3
// baseline (707.428 us; speedup 1.0000x reference)
//
#include <hip/hip_runtime.h>

// RetinaNet head via bf16 MFMA implicit-GEMM, 32x32x16 variant.
// Activations: padded NHWC bf16 [plane][(H+2)(W+2)][256], zero borders.
// Block: 64co x 256px (16x16 tile), 4 waves; wave = 64co x 64px as 2x2 of
// mfma_f32_32x32x16_bf16 (acc 2x2 x f32x16). K = 8 chunks(32ci) x 9 taps.
// LDS: X [quad4][384px][8ci] 24.5KB, W [tap9][kk2][cc2][lane64][8ci] 36.9KB,
// staged via global_load_lds dwordx4; all ds_read_b128 lane-consecutive.

typedef __attribute__((ext_vector_type(8))) short short8;
typedef __attribute__((ext_vector_type(4))) float floatx4;
typedef __attribute__((ext_vector_type(16))) float floatx16;

#define LVLTOT 14143  // sum of padded (H+2)(W+2) over 5 levels

__device__ __forceinline__ unsigned short f2bf(float f) {
  unsigned int u = __float_as_uint(f);
  unsigned int r = (u + 0x7fffu + ((u >> 16) & 1u)) >> 16;
  return (unsigned short)r;
}

__device__ __forceinline__ void gload_lds16(const void* g, void* l) {
  __builtin_amdgcn_global_load_lds(
      (const __attribute__((address_space(1))) unsigned int*)g,
      (__attribute__((address_space(3))) unsigned int*)l, 16, 0, 0);
}

// ---- border zero: only pad cells of the 8 activation planes need zeros ----
__global__ __launch_bounds__(256) void border_zero(
    unsigned short* __restrict__ bufA, unsigned short* __restrict__ bufB) {
  static const int Wpt[5] = {102, 52, 27, 15, 9};
  static const int LOFFt[6] = {0, 10404, 13108, 13837, 14062, 14143};
  int idx = blockIdx.x * 256 + threadIdx.x;
  if (idx >= LVLTOT * 32) return;
  int px = idx >> 5, oct = idx & 31;
  int l = 0;
  while (px >= LOFFt[l + 1]) l++;
  int local = px - LOFFt[l];
  int Wp = Wpt[l];
  int r = local / Wp, c = local - r * Wp;
  if (r != 0 && r != Wp - 1 && c != 0 && c != Wp - 1) return;
  int plane = blockIdx.y;  // 0..3 bufA, 4..7 bufB (X0 aliases bufB planes 2,3)
  unsigned short* base = (plane < 4)
                             ? (bufA + (size_t)plane * LVLTOT * 256)
                             : (bufB + (size_t)(plane - 4) * LVLTOT * 256);
  floatx4 z;
  z[0] = z[1] = z[2] = z[3] = 0.f;
  *(floatx4*)(base + (size_t)px * 256 + oct * 8) = z;
}

// ---- input prep (all 5 levels, one dispatch): NCHW fp32 -> padded NHWC bf16
__global__ __launch_bounds__(256) void xprep(
    const float* __restrict__ f0, const float* __restrict__ f1,
    const float* __restrict__ f2, const float* __restrict__ f3,
    const float* __restrict__ f4, unsigned short* __restrict__ x0) {
  static const int Ht[5] = {100, 50, 25, 13, 7};
  static const int Wpt[5] = {102, 52, 27, 15, 9};
  static const int LOFFt[5] = {0, 10404, 13108, 13837, 14062};
  __shared__ float ts[8][33];
  int bx = blockIdx.x;
  int l, h, wb;
  if (bx < 400)      { l = 0; h = bx >> 2;         wb = bx & 3; }
  else if (bx < 500) { l = 1; h = (bx - 400) >> 1; wb = (bx - 400) & 1; }
  else if (bx < 525) { l = 2; h = bx - 500; wb = 0; }
  else if (bx < 538) { l = 3; h = bx - 525; wb = 0; }
  else               { l = 4; h = bx - 538; wb = 0; }
  const float* f = l == 0 ? f0 : l == 1 ? f1 : l == 2 ? f2 : l == 3 ? f3 : f4;
  int H = Ht[l], W = H, Wp = Wpt[l], loff = LOFFt[l];
  int t = threadIdx.x;
  int w0 = wb * 32;
  int n = blockIdx.z >> 5, cbk = blockIdx.z & 31;
  int cl = t >> 5, wl = t & 31;
  float v = 0.f;
  if (w0 + wl < W)
    v = f[(((size_t)n * 256 + cbk * 8 + cl) * H + h) * W + w0 + wl];
  ts[cl][wl] = v;
  __syncthreads();
  int pi = t >> 3, cj = t & 7;
  if (w0 + pi < W)
    x0[((size_t)n * LVLTOT + loff + (size_t)(h + 1) * Wp + (w0 + pi + 1)) * 256 +
       cbk * 8 + cj] = f2bf(ts[cj][pi]);
}

// ---- weight prep: w[Cout][256][9] fp32 ->
//      blob[cb][ch][tap][kk][cc][lane64 = kh*32+co32][8ci] bf16
struct WPArgs {
  const float* src[10];
  unsigned short* dst[10];
  int cout[10];
  int coutp[10];
};
__global__ __launch_bounds__(256) void wprep(WPArgs A) {
  int id = blockIdx.y;
  int idx = blockIdx.x * 256 + threadIdx.x;
  int coutp = A.coutp[id];
  if (idx >= coutp * 256) return;
  int co = idx >> 8, ci = idx & 255;
  const float* w = A.src[id];
  unsigned short* dst = A.dst[id];
  bool valid = co < A.cout[id];
  int cb = co >> 6, cc = (co >> 5) & 1, co32 = co & 31;
  int ch = ci >> 5, ci5 = ci & 31;
  int kk = ci5 >> 4, kh = (ci5 >> 3) & 1, j = ci5 & 7;
#pragma unroll
  for (int tap = 0; tap < 9; tap++) {
    float v = valid ? w[((size_t)co * 256 + ci) * 9 + tap] : 0.f;
    dst[((((size_t)(cb * 8 + ch) * 9 + tap) * 2 + kk) * 2 + cc) * 512 +
        kh * 256 + co32 * 8 + j] = f2bf(v);
  }
}

// ---- tile decode (71 tiles over 5 levels) ----
__device__ __forceinline__ void decode_tile(int tile, int& l, int& h0, int& w0,
                                            int& H, int& W, int& Wp, int& loff) {
  const int Ht[5] = {100, 50, 25, 13, 7};
  const int Wpt[5] = {102, 52, 27, 15, 9};
  const int TXt[5] = {7, 4, 2, 1, 1};
  const int LOFFt[5] = {0, 10404, 13108, 13837, 14062};
  int tloc;
  if (tile < 49) { l = 0; tloc = tile; }
  else if (tile < 65) { l = 1; tloc = tile - 49; }
  else if (tile < 69) { l = 2; tloc = tile - 65; }
  else if (tile < 70) { l = 3; tloc = tile - 69; }
  else { l = 4; tloc = 0; }
  H = Ht[l]; W = H; Wp = Wpt[l]; loff = LOFFt[l];
  int ty = tloc / TXt[l], tx = tloc - ty * TXt[l];
  h0 = ty * 16; w0 = tx * 16;
}

// ---- K-loop body (needs: lane, wv, kh, rh, n15, h0, w0, Hpad, Wp,
//      lds_w, lds_x, acc[2][2]) ----
#define CONV_MAIN_LOOP(INP, WBLOB, CB)                                         \
  {                                                                            \
    size_t xoff[6];                                                            \
    _Pragma("unroll") for (int g = 0; g < 6; g++) {                            \
      int px = g * 64 + lane;                                                  \
      int r = px / 18, c = px - r * 18;                                        \
      int hh = h0 + r; if (hh > Hpad - 1) hh = Hpad - 1;                       \
      int ww = w0 + c; if (ww > Wp - 1) ww = Wp - 1;                           \
      xoff[g] = ((size_t)hh * Wp + ww) * 256 + wv * 8;                         \
    }                                                                          \
    for (int ch = 0; ch < 8; ch++) {                                           \
      if (ch) __syncthreads();                                                 \
      const unsigned short* wsrc = (WBLOB) + ((size_t)((CB)*8 + ch)) * 18432;  \
      _Pragma("unroll") for (int i = 0; i < 9; i++)                            \
        gload_lds16(wsrc + i * 2048 + wv * 512 + lane * 8,                     \
                    lds_w + i * 2048 + wv * 512);                              \
      _Pragma("unroll") for (int g = 0; g < 6; g++)                            \
        gload_lds16((INP) + xoff[g] + ch * 32, lds_x + wv * 3072 + g * 512);   \
      __syncthreads();                                                         \
      const short8* xw = (const short8*)lds_w;                                 \
      const short8* xx = (const short8*)lds_x;                                 \
      _Pragma("unroll") for (int tap = 0; tap < 9; tap++) {                    \
        const int tdy = tap / 3, tdx = tap - 3 * (tap / 3);                    \
        short8 bfr[2][2];                                                      \
        _Pragma("unroll") for (int kk = 0; kk < 2; kk++)                       \
          _Pragma("unroll") for (int rr = 0; rr < 2; rr++)                     \
            bfr[kk][rr] = xx[(kk * 2 + kh) * 384 +                             \
                             (wv * 4 + rr * 2 + rh + tdy) * 18 + n15 + tdx];   \
        _Pragma("unroll") for (int kk = 0; kk < 2; kk++)                       \
          _Pragma("unroll") for (int cc = 0; cc < 2; cc++) {                   \
            short8 afr = xw[((tap * 2 + kk) * 2 + cc) * 64 + lane];            \
            _Pragma("unroll") for (int rr = 0; rr < 2; rr++)                   \
              acc[cc][rr] = __builtin_amdgcn_mfma_f32_32x32x16_bf16(           \
                  afr, bfr[kk][rr], acc[cc][rr], 0, 0, 0);                     \
          }                                                                    \
      }                                                                        \
    }                                                                          \
  }

// ---- tower conv layer (bf16 in -> bf16 out, +bias, ReLU) ----
__global__ __launch_bounds__(256, 2) void conv_tower_mfma(
    const unsigned short* __restrict__ xin, unsigned short* __restrict__ xout,
    const unsigned short* __restrict__ wblob_cls,
    const unsigned short* __restrict__ wblob_box,
    const float* __restrict__ bias_cls, const float* __restrict__ bias_box,
    int in_n_stride, int in_tw_stride) {
  __shared__ __align__(16) unsigned short lds_w[18432];
  __shared__ __align__(16) unsigned short lds_x[12288];
  const int t = threadIdx.x, lane = t & 63, wv = t >> 6;
  const int kh = lane >> 5, rh = (lane >> 4) & 1, n15 = lane & 15;
  int l, h0, w0, H, W, Wp, loff;
  decode_tile(blockIdx.x, l, h0, w0, H, W, Wp, loff);
  const int Hpad = H + 2;
  const int cb = blockIdx.y;
  const int n = blockIdx.z >> 1, tw = blockIdx.z & 1;
  const unsigned short* wblob = tw ? wblob_box : wblob_cls;
  const float* bias = tw ? bias_box : bias_cls;
  const unsigned short* inp =
      xin + ((size_t)n * in_n_stride + (size_t)tw * in_tw_stride + loff) * 256;
  unsigned short* outp = xout + ((size_t)(n * 2 + tw) * LVLTOT + loff) * 256;

  floatx16 acc[2][2];
#pragma unroll
  for (int i = 0; i < 2; i++)
#pragma unroll
    for (int jj = 0; jj < 2; jj++)
#pragma unroll
      for (int e = 0; e < 16; e++) acc[i][jj][e] = 0.f;

  CONV_MAIN_LOOP(inp, wblob, cb)

#pragma unroll
  for (int cc = 0; cc < 2; cc++)
#pragma unroll
    for (int r2 = 0; r2 < 4; r2++) {
      int cob = cb * 64 + cc * 32 + 8 * r2 + 4 * kh;
      floatx4 bb = *(const floatx4*)(bias + cob);
#pragma unroll
      for (int rr = 0; rr < 2; rr++) {
        int h = h0 + wv * 4 + rr * 2 + rh;
        int w_ = w0 + n15;
        if (h < H && w_ < W) {
          unsigned short pk[4];
#pragma unroll
          for (int q4 = 0; q4 < 4; q4++)
            pk[q4] = f2bf(fmaxf(acc[cc][rr][r2 * 4 + q4] + bb[q4], 0.f));
          *(unsigned long long*)(outp + ((size_t)(h + 1) * Wp + (w_ + 1)) * 256 +
                                 cob) = *(unsigned long long*)pk;
        }
      }
    }
}

// ---- merged final conv (y<12: cls cb=y; y==12: box), permuted fp32 out ----
__global__ __launch_bounds__(256, 2) void conv_final_mfma(
    const unsigned short* __restrict__ xin, float* __restrict__ out,
    const unsigned short* __restrict__ wblob_cls,
    const unsigned short* __restrict__ wblob_box,
    const float* __restrict__ bias_cls, const float* __restrict__ bias_box) {
  __shared__ __align__(16) unsigned short lds_w[18432];
  __shared__ __align__(16) unsigned short lds_x[12288];
  const int t = threadIdx.x, lane = t & 63, wv = t >> 6;
  const int kh = lane >> 5, rh = (lane >> 4) & 1, n15 = lane & 15;
  int l, h0, w0, H, W, Wp, loff;
  decode_tile(blockIdx.x, l, h0, w0, H, W, Wp, loff);
  const int Hpad = H + 2;
  const int yb = blockIdx.y;
  const bool is_cls = yb < 12;
  const int cb = is_cls ? yb : 0;
  const int tw = is_cls ? 0 : 1;
  const int Cout = is_cls ? 720 : 36;
  const unsigned short* wblob = is_cls ? wblob_cls : wblob_box;
  const float* bias = is_cls ? bias_cls : bias_box;
  const int n = blockIdx.z;
  const int RB[5] = {0, 90000, 112500, 118125, 119646};
  const unsigned short* inp = xin + ((size_t)(n * 2 + tw) * LVLTOT + loff) * 256;

  floatx16 acc[2][2];
#pragma unroll
  for (int i = 0; i < 2; i++)
#pragma unroll
    for (int jj = 0; jj < 2; jj++)
#pragma unroll
      for (int e = 0; e < 16; e++) acc[i][jj][e] = 0.f;

  CONV_MAIN_LOOP(inp, wblob, cb)

#pragma unroll
  for (int cc = 0; cc < 2; cc++)
#pragma unroll
    for (int r2 = 0; r2 < 4; r2++) {
      int co0 = cb * 64 + cc * 32 + 8 * r2 + 4 * kh;
      if (co0 >= Cout) continue;
      floatx4 bb = *(const floatx4*)(bias + co0);
      int a = is_cls ? (co0 / 80) : (co0 >> 2);
      int col0 = is_cls ? (co0 - a * 80) : 80;
#pragma unroll
      for (int rr = 0; rr < 2; rr++) {
        int h = h0 + wv * 4 + rr * 2 + rh;
        int w_ = w0 + n15;
        if (h < H && w_ < W) {
          size_t ridx = (size_t)RB[l] + ((size_t)h * W + w_) * 9 + a;
          floatx4 v;
#pragma unroll
          for (int q4 = 0; q4 < 4; q4++) v[q4] = acc[cc][rr][r2 * 4 + q4] + bb[q4];
          *(floatx4*)(out + ((size_t)n * 120087 + ridx) * 84 + col0) = v;
        }
      }
    }
}

extern "C" void kernel_launch(void* const* d_in, const int* in_sizes, int n_in,
                              void* d_out, int out_size, void* d_ws,
                              size_t ws_size, hipStream_t stream) {
  // ws layout (bytes):
  //   bufB [0, 28964864)    (X0 aliased to bufB planes 2,3: dead after layer 1)
  //   X0   [14482432, 28964864)
  //   bufA [28964864, 57929728)
  //   tower blobs 8 x 1179648 at 57929728 (cls0..3, box0..3)
  //   cls final blob 3538944 at 67366912; box final blob 294912 at 70905856
  char* ws = (char*)d_ws;
  unsigned short* bufB = (unsigned short*)(ws);
  unsigned short* X0 = (unsigned short*)(ws + 14482432);
  unsigned short* bufA = (unsigned short*)(ws + 28964864);
  unsigned short* tb[8];
  for (int i = 0; i < 8; i++)
    tb[i] = (unsigned short*)(ws + 57929728 + (size_t)i * 1179648);
  unsigned short* fb_cls = (unsigned short*)(ws + 67366912);
  unsigned short* fb_box = (unsigned short*)(ws + 70905856);

  float* out = (float*)d_out;

  border_zero<<<dim3((LVLTOT * 32 + 255) / 256, 8), 256, 0, stream>>>(bufA, bufB);
  xprep<<<dim3(545, 1, 64), 256, 0, stream>>>(
      (const float*)d_in[0], (const float*)d_in[1], (const float*)d_in[2],
      (const float*)d_in[3], (const float*)d_in[4], X0);

  WPArgs wa;
  for (int i = 0; i < 4; i++) {
    wa.src[i] = (const float*)d_in[5 + 2 * i];       // cls_w0..3
    wa.src[4 + i] = (const float*)d_in[13 + 2 * i];  // box_w0..3
    wa.dst[i] = tb[i];
    wa.dst[4 + i] = tb[4 + i];
    wa.cout[i] = wa.cout[4 + i] = 256;
    wa.coutp[i] = wa.coutp[4 + i] = 256;
  }
  wa.src[8] = (const float*)d_in[21]; wa.dst[8] = fb_cls;
  wa.cout[8] = 720; wa.coutp[8] = 768;
  wa.src[9] = (const float*)d_in[23]; wa.dst[9] = fb_box;
  wa.cout[9] = 36; wa.coutp[9] = 64;
  wprep<<<dim3(768, 10), 256, 0, stream>>>(wa);

  const float *cls_b[4], *box_b[4];
  for (int i = 0; i < 4; i++) {
    cls_b[i] = (const float*)d_in[6 + 2 * i];
    box_b[i] = (const float*)d_in[14 + 2 * i];
  }

  dim3 gt(71, 4, 4);
  conv_tower_mfma<<<gt, 256, 0, stream>>>(X0, bufA, tb[0], tb[4], cls_b[0],
                                          box_b[0], LVLTOT, 0);
  conv_tower_mfma<<<gt, 256, 0, stream>>>(bufA, bufB, tb[1], tb[5], cls_b[1],
                                          box_b[1], 2 * LVLTOT, LVLTOT);
  conv_tower_mfma<<<gt, 256, 0, stream>>>(bufB, bufA, tb[2], tb[6], cls_b[2],
                                          box_b[2], 2 * LVLTOT, LVLTOT);
  conv_tower_mfma<<<gt, 256, 0, stream>>>(bufA, bufB, tb[3], tb[7], cls_b[3],
                                          box_b[3], 2 * LVLTOT, LVLTOT);

  conv_final_mfma<<<dim3(71, 13, 2), 256, 0, stream>>>(
      bufB, out, fb_cls, fb_box, (const float*)d_in[22], (const float*)d_in[24]);
}